// Round 9
// baseline (2169.396 us; speedup 1.0000x reference)
//
#include <hip/hip_runtime.h>
#include <hip/hip_bf16.h>

typedef __hip_bfloat16 bf16;
typedef __attribute__((ext_vector_type(8))) short bf16x8;
typedef __attribute__((ext_vector_type(4))) float f32x4;

#define N_NODE   50000
#define N_EDGE   800000
#define N_QUERY  512
#define EPW      8
#define NB_SCAN  196   // ceil(50000/256)

__device__ __forceinline__ float bfbits2f(unsigned short u) {
    return __uint_as_float(((unsigned)u) << 16);
}
__device__ __forceinline__ unsigned short f2bfbits(float f) {
    unsigned int u = __float_as_uint(f);
    return (unsigned short)((u + 0x7fffu + ((u >> 16) & 1u)) >> 16);  // RNE
}
__device__ __forceinline__ float lrelu(float x) { return x > 0.f ? x : 0.01f * x; }
__device__ __forceinline__ float dot4(float4 a, float4 b, float acc) {
    acc = fmaf(a.x, b.x, acc); acc = fmaf(a.y, b.y, acc);
    acc = fmaf(a.z, b.z, acc); acc = fmaf(a.w, b.w, acc);
    return acc;
}
__device__ __forceinline__ void atom_pk_bf16(unsigned int* addr, float a0, float a1) {
    unsigned int old = *((volatile unsigned int*)addr);
    while (true) {
        float f0 = bfbits2f((unsigned short)(old & 0xffffu)) + a0;
        float f1 = bfbits2f((unsigned short)(old >> 16)) + a1;
        unsigned int nv = (unsigned int)f2bfbits(f0) | ((unsigned int)f2bfbits(f1) << 16);
        unsigned int prev = atomicCAS(addr, old, nv);
        if (prev == old) break;
        old = prev;
    }
}

// ---------- dtype detection (pe[0] word: fp32 -> 0x00000000, bf16 -> 0x3F800000) ----------
__global__ void k_detect(const unsigned int* __restrict__ pe_raw, int* __restrict__ flag) {
    *flag = (pe_raw[0] != 0u) ? 1 : 0;   // 1 = bf16 inputs, 0 = fp32 inputs
}

// ---------- zero: gather mode zeroes hist; compact mode zeroes bot + d_out ----------
__global__ void k_zero(unsigned int* __restrict__ out_w, int out_elems,
                       const int* __restrict__ flag, float* __restrict__ bot,
                       int* __restrict__ hist, int gather_mode) {
    int f = *flag;
    int stride = gridDim.x * blockDim.x;
    int tid = blockIdx.x * blockDim.x + threadIdx.x;
    if (gather_mode) {
        for (int i = tid; i < N_NODE; i += stride) hist[i] = 0;
    } else {
        for (int i = tid; i < N_NODE; i += stride) bot[i] = 0.f;
        int out_words = f ? (out_elems >> 1) : out_elems;
        for (int i = tid; i < out_words; i += stride) out_w[i] = 0u;
    }
}

// ---------- convert all small tensors to fp32 pool (transposes W2/Ws/Wr/Wqr) ----------
#define SEG_RELA   51328
#define SEG_PE     32000
#define SEG_W1     20480
#define SEG_B1     128
#define SEG_W2T    16384
#define SEG_B2     128
#define SEG_WST    8192
#define SEG_WRT    8192
#define SEG_WQRT   8192
#define SEG_BQR    64
#define SEG_WA     64
#define SEG_WH     16384
#define POOL_TOTAL (SEG_RELA+SEG_PE+SEG_W1+SEG_B1+SEG_W2T+SEG_B2+SEG_WST+SEG_WRT+SEG_WQRT+SEG_BQR+SEG_WA+SEG_WH)

__global__ void k_convert(const void* rela, const void* pe, const void* W1, const void* b1,
                          const void* W2, const void* b2, const void* Ws, const void* Wr,
                          const void* Wqr, const void* bqr, const void* walpha, const void* Wh,
                          const int* __restrict__ flag, float* __restrict__ pool) {
    int idx = blockIdx.x * blockDim.x + threadIdx.x;
    int f = *flag;
    auto ld = [&](const void* p, int i) -> float {
        return f ? __bfloat162float(((const bf16*)p)[i]) : ((const float*)p)[i];
    };
    int i = idx;
    if (i < SEG_RELA) { pool[idx] = ld(rela, i); return; } i -= SEG_RELA;
    if (i < SEG_PE)   { pool[idx] = ld(pe, i); return; }   i -= SEG_PE;
    if (i < SEG_W1)   { pool[idx] = ld(W1, i); return; }   i -= SEG_W1;
    if (i < SEG_B1)   { pool[idx] = ld(b1, i); return; }   i -= SEG_B1;
    if (i < SEG_W2T)  { pool[idx] = ld(W2, (i & 127) * 128 + (i >> 7)); return; } i -= SEG_W2T;
    if (i < SEG_B2)   { pool[idx] = ld(b2, i); return; }   i -= SEG_B2;
    if (i < SEG_WST)  { pool[idx] = ld(Ws,  (i & 127) * 64 + (i >> 7)); return; } i -= SEG_WST;
    if (i < SEG_WRT)  { pool[idx] = ld(Wr,  (i & 127) * 64 + (i >> 7)); return; } i -= SEG_WRT;
    if (i < SEG_WQRT) { pool[idx] = ld(Wqr, (i & 127) * 64 + (i >> 7)); return; } i -= SEG_WQRT;
    if (i < SEG_BQR)  { pool[idx] = ld(bqr, i); return; }  i -= SEG_BQR;
    if (i < SEG_WA)   { pool[idx] = ld(walpha, i); return; } i -= SEG_WA;
    if (i < SEG_WH)   { pool[idx] = ld(Wh, i); return; }
}

// ---------- pack W2/Wr into MFMA B-fragment order (bf16) ----------
__global__ void k_pack(const float* __restrict__ W2T_f, const float* __restrict__ WrT_f,
                       short* __restrict__ W2pk, short* __restrict__ Wrpk) {
    int idx = blockIdx.x * blockDim.x + threadIdx.x;
    if (idx < 16384) {
        int j = idx & 7, lane = (idx >> 3) & 63, kb = (idx >> 9) & 3, nt = idx >> 11;
        int k = kb * 32 + (lane >> 4) * 8 + j, n = nt * 16 + (lane & 15);
        W2pk[idx] = (short)f2bfbits(W2T_f[n * 128 + k]);
    } else if (idx < 16384 + 8192) {
        int i2 = idx - 16384;
        int j = i2 & 7, lane = (i2 >> 3) & 63, kb = (i2 >> 9) & 3, nt = i2 >> 11;
        int k = kb * 32 + (lane >> 4) * 8 + j, n = nt * 16 + (lane & 15);
        Wrpk[i2] = (short)f2bfbits(WrT_f[n * 128 + k]);
    }
}

// ---------- precompute tables ----------
__global__ void k_arel(const float* __restrict__ rela_f, const float* __restrict__ W1_f,
                       float* __restrict__ A_rel, unsigned short* __restrict__ relcat) {
    __shared__ float ld[128];
    int r = blockIdx.x, j = threadIdx.x;
    float rv = rela_f[r * 128 + j];
    ld[j] = rv;
    __syncthreads();
    float acc = 0.f;
    for (int k = 0; k < 128; k++) acc = fmaf(ld[k], W1_f[k * 128 + j], acc);
    A_rel[r * 128 + j] = acc;
    relcat[r * 256 + j] = f2bfbits(acc);
    relcat[r * 256 + 128 + j] = f2bfbits(rv);
}

__global__ void k_atime(const float* __restrict__ pe_f, const float* __restrict__ W1_f,
                        const float* __restrict__ b1_f, float* __restrict__ A_timeb,
                        unsigned short* __restrict__ atimb) {
    __shared__ float ld[32];
    int t = blockIdx.x, j = threadIdx.x;
    if (j < 32) ld[j] = pe_f[t * 32 + j];
    __syncthreads();
    float acc = b1_f[j];
    for (int k = 0; k < 32; k++) acc = fmaf(ld[k], W1_f[(128 + k) * 128 + j], acc);
    A_timeb[t * 128 + j] = acc;
    atimb[t * 128 + j] = f2bfbits(acc);
}

__global__ void k_qws(const float* __restrict__ rela_f, const int* __restrict__ q_rel,
                      const float* __restrict__ bqr_f, const float* __restrict__ WqrT_f,
                      float* __restrict__ Q_ws) {
    alignas(16) __shared__ float qrow[4][128];
    int wv = threadIdx.x >> 6, lane = threadIdx.x & 63;
    int q = blockIdx.x * 4 + wv;
    int qr = q_rel[q];
    const float2* rp = (const float2*)(rela_f + qr * 128);
    float2 rv = rp[lane];
    qrow[wv][2 * lane] = rv.x;
    qrow[wv][2 * lane + 1] = rv.y;
    __syncthreads();
    const float4* wp = (const float4*)(WqrT_f + lane * 128);
    const float4* qp4 = (const float4*)qrow[wv];
    float acc = bqr_f[lane];
    for (int k4 = 0; k4 < 32; k4++) acc = dot4(qp4[k4], wp[k4], acc);
    Q_ws[q * 64 + lane] = acc;
}

// hn bf16 [50000][192] = (hidden | S_node); wave per node
__global__ void k_hn(const void* __restrict__ hidden, const float* __restrict__ WsT_f,
                     const int* __restrict__ flag, unsigned short* __restrict__ hn) {
    alignas(16) __shared__ float hrow[4][128];
    int wv = threadIdx.x >> 6, lane = threadIdx.x & 63;
    int n = blockIdx.x * 4 + wv;
    int f = *flag;
    float h0, h1;
    if (f) {
        ushort2 hv = ((const ushort2*)((const bf16*)hidden + n * 128))[lane];
        h0 = bfbits2f(hv.x); h1 = bfbits2f(hv.y);
    } else {
        float2 hv = ((const float2*)((const float*)hidden + n * 128))[lane];
        h0 = hv.x; h1 = hv.y;
    }
    hrow[wv][2 * lane] = h0;
    hrow[wv][2 * lane + 1] = h1;
    *((unsigned int*)&hn[n * 192 + 2 * lane]) =
        (unsigned)f2bfbits(h0) | ((unsigned)f2bfbits(h1) << 16);
    __syncthreads();
    const float4* wp = (const float4*)(WsT_f + lane * 128);
    const float4* hp4 = (const float4*)hrow[wv];
    float acc = 0.f;
    for (int k4 = 0; k4 < 32; k4++) acc = dot4(hp4[k4], wp[k4], acc);
    hn[n * 192 + 128 + lane] = f2bfbits(acc);
}

// ---------- counting sort by obj ----------
__global__ void k_hist(const int* __restrict__ edges, int* __restrict__ hist) {
    int i = blockIdx.x * blockDim.x + threadIdx.x;
    if (i < N_EDGE) atomicAdd(&hist[edges[i * 7 + 5]], 1);
}

__global__ void k_scan_part(const int* __restrict__ hist, int* __restrict__ start,
                            int* __restrict__ blocksum) {
    __shared__ int s[256];
    int t = threadIdx.x, b = blockIdx.x, i = b * 256 + t;
    int v = (i < N_NODE) ? hist[i] : 0;
    s[t] = v;
    __syncthreads();
    for (int off = 1; off < 256; off <<= 1) {
        int x = (t >= off) ? s[t - off] : 0;
        __syncthreads();
        s[t] += x;
        __syncthreads();
    }
    if (i < N_NODE) start[i] = s[t] - v;          // exclusive
    if (t == 255) blocksum[b] = s[t];
}

__global__ void k_scan_top(int* __restrict__ blocksum, int* __restrict__ blockoff) {
    __shared__ int s[256];
    int t = threadIdx.x;
    int v = (t < NB_SCAN) ? blocksum[t] : 0;
    s[t] = v;
    __syncthreads();
    for (int off = 1; off < 256; off <<= 1) {
        int x = (t >= off) ? s[t - off] : 0;
        __syncthreads();
        s[t] += x;
        __syncthreads();
    }
    if (t < NB_SCAN) blockoff[t] = s[t] - v;      // exclusive
}

__global__ void k_scan_add(int* __restrict__ start, const int* __restrict__ blockoff,
                           int* __restrict__ cursor) {
    int t = threadIdx.x, b = blockIdx.x, i = b * 256 + t;
    if (i < N_NODE) {
        int sv = start[i] + blockoff[b];
        start[i] = sv;
        cursor[i] = sv;
    }
}

__global__ void k_scat(const int* __restrict__ edges, int* __restrict__ cursor,
                       int2* __restrict__ sorted2) {
    int i = blockIdx.x * blockDim.x + threadIdx.x;
    if (i < N_EDGE) {
        const int* ep = edges + i * 7;
        int p = atomicAdd(&cursor[ep[5]], 1);
        sorted2[p] = make_int2(ep[4] | (ep[0] << 16), ep[2] | (ep[6] << 16));
    }
}

// ---------- GATHER edge kernel: nt streaming loads, coalesced staging ----------
__global__ __launch_bounds__(256, 4) void k_edge_g(
        const int2* __restrict__ sorted2, const int* __restrict__ start,
        const int* __restrict__ deg,
        const unsigned short* __restrict__ hn,       // [n][192] hidden|S_node bf16
        const unsigned short* __restrict__ relcat,   // [r][256] A_rel|rela bf16
        const unsigned short* __restrict__ atimb,    // [t][128] bf16
        const short* __restrict__ W2pk, const short* __restrict__ Wrpk,
        const float* __restrict__ b2_f, const float* __restrict__ Q_ws,
        const float* __restrict__ wa_f, const float* __restrict__ Wh_f,
        const int* __restrict__ flag, void* __restrict__ dout) {
    alignas(16) __shared__ short buf[4][16][136];    // h / hr rows (bf16)
    alignas(16) __shared__ unsigned short srow[4][16][72];  // S_node rows (bf16)
    int wv = threadIdx.x >> 6, lane = threadIdx.x & 63;
    int c = lane & 15, q = lane >> 4;
    int f = *flag;
    int n = blockIdx.x * 4 + wv;                    // 12500*4 = 50000 exact
    int s = start[n], d = deg[n];

    float wa4[4];
#pragma unroll
    for (int nt = 0; nt < 4; nt++) wa4[nt] = wa_f[nt * 16 + c];

    short (*bw)[136] = buf[wv];
    unsigned short (*sw)[72] = srow[wv];
    float up0 = 0.f, up1 = 0.f, bsum = 0.f;

    for (int c0 = 0; c0 < d; c0 += 16) {
        int m = min(16, d - c0);
        int w0 = 0, w1 = 0;
        if (lane < m) {
            unsigned long long r = __builtin_nontemporal_load(
                (const unsigned long long*)(sorted2 + s + c0 + lane));
            w0 = (int)(r & 0xffffffffull);
            w1 = (int)(r >> 32);
        }

        // stage h = lrelu(A_rel + A_timeb) and S_node row (both coalesced)
#pragma unroll
        for (int e = 0; e < 16; e++) {
            int w1e = __shfl(w1, e);
            int w0e = __shfl(w0, e);
            int rel_e = w1e & 0xffff, tim_e = w1e >> 16, sub_e = w0e & 0xffff;
            ushort2 a = ((const ushort2*)(relcat + rel_e * 256))[lane];
            ushort2 t = ((const ushort2*)(atimb + tim_e * 128))[lane];
            float h0 = lrelu(bfbits2f(a.x) + bfbits2f(t.x));
            float h1 = lrelu(bfbits2f(a.y) + bfbits2f(t.y));
            *((unsigned int*)&bw[e][2 * lane]) =
                (unsigned)f2bfbits(h0) | ((unsigned)f2bfbits(h1) << 16);
            sw[e][lane] = __builtin_nontemporal_load(hn + sub_e * 192 + 128 + lane);
        }

        bf16x8 hf[4];
#pragma unroll
        for (int kb = 0; kb < 4; kb++)
            hf[kb] = *((const bf16x8*)&bw[c][kb * 32 + q * 8]);

        // h2 = lrelu(h@W2 + b2) -> buf (D-layout writes)
#pragma unroll
        for (int nt = 0; nt < 8; nt++) {
            f32x4 acc = {0.f, 0.f, 0.f, 0.f};
#pragma unroll
            for (int kb = 0; kb < 4; kb++) {
                bf16x8 bfr = *((const bf16x8*)(W2pk + (((nt * 4 + kb) * 64) + lane) * 8));
                acc = __builtin_amdgcn_mfma_f32_16x16x32_bf16(hf[kb], bfr, acc, 0, 0, 0);
            }
            int colg = nt * 16 + c;
            float b2v = b2_f[colg];
#pragma unroll
            for (int r = 0; r < 4; r++) {
                int er = q * 4 + r;
                bw[er][colg] = (short)f2bfbits(lrelu(acc[r] + b2v));
            }
        }

        // hr = h2 + rel_e: coalesced rela read + LDS fixup (per-row, per-lane)
#pragma unroll
        for (int e = 0; e < 16; e++) {
            int rel_e = __shfl(w1, e) & 0xffff;
            ushort2 rv = ((const ushort2*)(relcat + rel_e * 256 + 128))[lane];
            unsigned int pk = *((const unsigned int*)&bw[e][2 * lane]);
            float v0 = bfbits2f((unsigned short)(pk & 0xffffu)) + bfbits2f(rv.x);
            float v1 = bfbits2f((unsigned short)(pk >> 16)) + bfbits2f(rv.y);
            *((unsigned int*)&bw[e][2 * lane]) =
                (unsigned)f2bfbits(v0) | ((unsigned)f2bfbits(v1) << 16);
        }

        bf16x8 hrf[4];
#pragma unroll
        for (int kb = 0; kb < 4; kb++)
            hrf[kb] = *((const bf16x8*)&bw[c][kb * 32 + q * 8]);

        // att = lrelu(S_node + Q_ws + hr@Wr) . w_alpha
        float asum[4] = {0.f, 0.f, 0.f, 0.f};
#pragma unroll
        for (int nt = 0; nt < 4; nt++) {
            f32x4 acc = {0.f, 0.f, 0.f, 0.f};
#pragma unroll
            for (int kb = 0; kb < 4; kb++) {
                bf16x8 bfr = *((const bf16x8*)(Wrpk + (((nt * 4 + kb) * 64) + lane) * 8));
                acc = __builtin_amdgcn_mfma_f32_16x16x32_bf16(hrf[kb], bfr, acc, 0, 0, 0);
            }
            int colg = nt * 16 + c;
#pragma unroll
            for (int r = 0; r < 4; r++) {
                int er = q * 4 + r;
                int qi_e = __shfl(w0, er) >> 16;
                float av = acc[r] + bfbits2f(sw[er][colg]) + Q_ws[qi_e * 64 + colg];
                asum[r] += lrelu(av) * wa4[nt];
            }
        }
        float ea[4];
#pragma unroll
        for (int r = 0; r < 4; r++) {
            float a = asum[r];
            a += __shfl_xor(a, 1); a += __shfl_xor(a, 2);
            a += __shfl_xor(a, 4); a += __shfl_xor(a, 8);
            ea[r] = (q * 4 + r < m) ? __expf(a) : 0.f;
        }

        // accumulate into the node's up-row (registers); hidden via nt loads
#pragma unroll
        for (int e = 0; e < 16; e++) {
            if (e < m) {   // m is wave-uniform
                float eav = __shfl(ea[e & 3], (e >> 2) * 16);
                unsigned int pk = *((const unsigned int*)&bw[e][2 * lane]);
                float hr0 = bfbits2f((unsigned short)(pk & 0xffffu));
                float hr1 = bfbits2f((unsigned short)(pk >> 16));
                int sub_e = __shfl(w0, e) & 0xffff;
                unsigned int hv = __builtin_nontemporal_load(
                    (const unsigned int*)(hn + sub_e * 192) + lane);
                up0 += eav * (bfbits2f((unsigned short)(hv & 0xffffu)) + hr0);
                up1 += eav * (bfbits2f((unsigned short)(hv >> 16)) + hr1);
                bsum += eav;
            }
        }
    }

    // fused epilogue: out[n] = (up/bot) @ Wh
    float inv = 1.f / (bsum + 1e-5f);
    float* mrow = (float*)&bw[0][0];   // reuse wave-private LDS
    mrow[2 * lane] = up0 * inv;
    mrow[2 * lane + 1] = up1 * inv;
    float o0 = 0.f, o1 = 0.f;
    for (int k = 0; k < 128; k++) {
        float mk = mrow[k];
        float2 w = ((const float2*)(Wh_f + k * 128))[lane];
        o0 = fmaf(mk, w.x, o0);
        o1 = fmaf(mk, w.y, o1);
    }
    if (f) {
        __builtin_nontemporal_store(
            (unsigned)f2bfbits(o0) | ((unsigned)f2bfbits(o1) << 16),
            (unsigned int*)dout + n * 64 + lane);
    } else {
        ((float2*)dout)[n * 64 + lane] = make_float2(o0, o1);
    }
}

// ---------- COMPACT-tier fallback (atomics into d_out) ----------
__global__ __launch_bounds__(256) void k_edge_c(
        const int* __restrict__ edges, const void* __restrict__ hidden,
        const float* __restrict__ rela_f,
        const float* __restrict__ A_rel, const float* __restrict__ A_timeb,
        const float* __restrict__ W2T, const float* __restrict__ WrT,
        const float* __restrict__ WsT, const float* __restrict__ b2_f,
        const float* __restrict__ Q_ws, const float* __restrict__ wa_f,
        const int* __restrict__ flag,
        float* __restrict__ bot, void* __restrict__ dout) {
    alignas(16) __shared__ float lds_h[4][EPW][128];
    alignas(16) __shared__ float lds_hr[4][EPW][128];
    alignas(16) __shared__ float lds_hs[4][EPW][128];
    int wv = threadIdx.x >> 6, lane = threadIdx.x & 63;
    int f = *flag;
    int nwaves = gridDim.x * 4;
    const int ngroups = N_EDGE / EPW;
    float b20 = b2_f[2 * lane], b21 = b2_f[2 * lane + 1];
    float wa = wa_f[lane];
    for (int g = blockIdx.x * 4 + wv; g < ngroups; g += nwaves) {
        int base = g * EPW;
        int rel[EPW], sub[EPW], obj[EPW], qi[EPW], tim[EPW];
#pragma unroll
        for (int e = 0; e < EPW; e++) {
            const int* ep = edges + (base + e) * 7;
            qi[e] = ep[0]; rel[e] = ep[2]; sub[e] = ep[4];
            obj[e] = ep[5]; tim[e] = ep[6];
        }
        float hs0[EPW], hs1[EPW];
#pragma unroll
        for (int e = 0; e < EPW; e++) {
            const float2* ar = (const float2*)(A_rel + rel[e] * 128);
            const float2* at = (const float2*)(A_timeb + tim[e] * 128);
            float2 a = ar[lane], t = at[lane];
            lds_h[wv][e][2 * lane]     = lrelu(a.x + t.x);
            lds_h[wv][e][2 * lane + 1] = lrelu(a.y + t.y);
            if (f) {
                ushort2 hv = ((const ushort2*)((const bf16*)hidden + sub[e] * 128))[lane];
                hs0[e] = bfbits2f(hv.x); hs1[e] = bfbits2f(hv.y);
            } else {
                float2 hv = ((const float2*)((const float*)hidden + sub[e] * 128))[lane];
                hs0[e] = hv.x; hs1[e] = hv.y;
            }
            lds_hs[wv][e][2 * lane]     = hs0[e];
            lds_hs[wv][e][2 * lane + 1] = hs1[e];
        }
        float acc0[EPW], acc1[EPW];
#pragma unroll
        for (int e = 0; e < EPW; e++) { acc0[e] = b20; acc1[e] = b21; }
        const float4* w0p = (const float4*)(W2T + (2 * lane) * 128);
        const float4* w1p = (const float4*)(W2T + (2 * lane + 1) * 128);
        for (int k4 = 0; k4 < 32; k4++) {
            float4 w0 = w0p[k4], w1 = w1p[k4];
#pragma unroll
            for (int e = 0; e < EPW; e++) {
                float4 h = ((const float4*)lds_h[wv][e])[k4];
                acc0[e] = dot4(h, w0, acc0[e]);
                acc1[e] = dot4(h, w1, acc1[e]);
            }
        }
        float hr0[EPW], hr1[EPW];
#pragma unroll
        for (int e = 0; e < EPW; e++) {
            const float2* rp = (const float2*)(rela_f + rel[e] * 128);
            float2 rv = rp[lane];
            hr0[e] = lrelu(acc0[e]) + rv.x;
            hr1[e] = lrelu(acc1[e]) + rv.y;
            lds_hr[wv][e][2 * lane]     = hr0[e];
            lds_hr[wv][e][2 * lane + 1] = hr1[e];
        }
        float att[EPW];
#pragma unroll
        for (int e = 0; e < EPW; e++) att[e] = Q_ws[qi[e] * 64 + lane];
        const float4* wrp = (const float4*)(WrT + lane * 128);
        const float4* wsp = (const float4*)(WsT + lane * 128);
        for (int k4 = 0; k4 < 32; k4++) {
            float4 w = wrp[k4], w2 = wsp[k4];
#pragma unroll
            for (int e = 0; e < EPW; e++) {
                float4 hr4 = ((const float4*)lds_hr[wv][e])[k4];
                float4 hs4 = ((const float4*)lds_hs[wv][e])[k4];
                att[e] = dot4(hr4, w, att[e]);
                att[e] = dot4(hs4, w2, att[e]);
            }
        }
        float ea[EPW];
#pragma unroll
        for (int e = 0; e < EPW; e++) {
            float a = lrelu(att[e]) * wa;
            a += __shfl_xor(a, 32); a += __shfl_xor(a, 16); a += __shfl_xor(a, 8);
            a += __shfl_xor(a, 4);  a += __shfl_xor(a, 2);  a += __shfl_xor(a, 1);
            ea[e] = __expf(a);
        }
#pragma unroll
        for (int e = 0; e < EPW; e++) {
            float v0 = ea[e] * (hs0[e] + hr0[e]);
            float v1 = ea[e] * (hs1[e] + hr1[e]);
            if (!f) {
                float* dst = (float*)dout + obj[e] * 128 + 2 * lane;
                unsafeAtomicAdd(dst,     v0);
                unsafeAtomicAdd(dst + 1, v1);
            } else {
                atom_pk_bf16((unsigned int*)dout + obj[e] * 64 + lane, v0, v1);
            }
            if (lane == 0) unsafeAtomicAdd(bot + obj[e], ea[e]);
        }
    }
}

// ---------- compact-mode epilogue (in-place on d_out) ----------
__global__ void k_out(const float* __restrict__ bot, const float* __restrict__ Wh_f,
                      void* __restrict__ dout, const int* __restrict__ flag) {
    __shared__ float m[2][128];
    int half = threadIdx.x >> 7, j = threadIdx.x & 127;
    int n = blockIdx.x * 2 + half;
    int f = *flag;
    float inv = 1.f / (bot[n] + 1e-5f);
    float num;
    if (!f) {
        num = ((const float*)dout)[n * 128 + j];
    } else {
        unsigned int w = ((const unsigned int*)dout)[n * 64 + (j >> 1)];
        num = bfbits2f((unsigned short)((j & 1) ? (w >> 16) : (w & 0xffffu)));
    }
    m[half][j] = num * inv;
    __syncthreads();
    float acc = 0.f;
    for (int k = 0; k < 128; k++) acc = fmaf(m[half][k], Wh_f[k * 128 + j], acc);
    if (f) ((bf16*)dout)[n * 128 + j] = __float2bfloat16(acc);
    else   ((float*)dout)[n * 128 + j] = acc;
}

// ---------- launcher ----------
extern "C" void kernel_launch(void* const* d_in, const int* in_sizes, int n_in,
                              void* d_out, int out_size, void* d_ws, size_t ws_size,
                              hipStream_t stream) {
    const void* hidden = d_in[0];
    const void* rela   = d_in[1];
    const void* pe     = d_in[2];
    const void* W1     = d_in[3];
    const void* b1     = d_in[4];
    const void* W2     = d_in[5];
    const void* b2     = d_in[6];
    const void* Ws     = d_in[7];
    const void* Wr     = d_in[8];
    const void* Wqr    = d_in[9];
    const void* bqr    = d_in[10];
    const void* walpha = d_in[11];
    const void* Wh     = d_in[12];
    const int* q_rel   = (const int*)d_in[13];
    const int* edges   = (const int*)d_in[14];

    float* ws = (float*)d_ws;
    size_t off = 0;
    int*   flag    = (int*)(ws + off); off += 4;
    float* pool    = ws + off;
    float* rela_f  = pool;
    float* pe_f    = rela_f + SEG_RELA;
    float* W1_f    = pe_f + SEG_PE;
    float* b1_f    = W1_f + SEG_W1;
    float* W2T_f   = b1_f + SEG_B1;
    float* b2_f    = W2T_f + SEG_W2T;
    float* WsT_f   = b2_f + SEG_B2;
    float* WrT_f   = WsT_f + SEG_WST;
    float* WqrT_f  = WrT_f + SEG_WRT;
    float* bqr_f   = WqrT_f + SEG_WQRT;
    float* wa_f    = bqr_f + SEG_BQR;
    float* Wh_f    = wa_f + SEG_WA;
    off += POOL_TOTAL;
    float* A_rel   = ws + off; off += 401 * 128;
    float* A_timeb = ws + off; off += 1000 * 128;
    float* Q_ws    = ws + off; off += N_QUERY * 64;
    float* bot     = ws + off; off += N_NODE;
    short* W2pk    = (short*)(ws + off); off += 8192;
    short* Wrpk    = (short*)(ws + off); off += 4096;
    int*   hist    = (int*)(ws + off); off += N_NODE;
    int*   startA  = (int*)(ws + off); off += N_NODE;
    int*   cursor  = (int*)(ws + off); off += N_NODE;
    int*   bsums   = (int*)(ws + off); off += 256;
    int*   boffs   = (int*)(ws + off); off += 256;
    unsigned short* relcat = (unsigned short*)(ws + off); off += 401 * 128;       // 401*256 bf16
    unsigned short* atimb  = (unsigned short*)(ws + off); off += 1000 * 64;       // 1000*128 bf16
    unsigned short* hn     = (unsigned short*)(ws + off); off += (size_t)N_NODE * 96; // 50000*192 bf16
    int2*  sorted2 = (int2*)(ws + off); off += (size_t)N_EDGE * 2;
    size_t gather_floats = off;

    int gather_ok = (ws_size >= gather_floats * sizeof(float)) ? 1 : 0;

    k_detect<<<1, 1, 0, stream>>>((const unsigned int*)pe, flag);
    k_zero<<<512, 256, 0, stream>>>((unsigned int*)d_out, out_size, flag, bot, hist, gather_ok);
    k_convert<<<(POOL_TOTAL + 255) / 256, 256, 0, stream>>>(
        rela, pe, W1, b1, W2, b2, Ws, Wr, Wqr, bqr, walpha, Wh, flag, pool);
    k_arel<<<401, 128, 0, stream>>>(rela_f, W1_f, A_rel, relcat);
    k_atime<<<1000, 128, 0, stream>>>(pe_f, W1_f, b1_f, A_timeb, atimb);
    k_qws<<<N_QUERY / 4, 256, 0, stream>>>(rela_f, q_rel, bqr_f, WqrT_f, Q_ws);

    if (gather_ok) {
        k_pack<<<96, 256, 0, stream>>>(W2T_f, WrT_f, W2pk, Wrpk);
        k_hn<<<N_NODE / 4, 256, 0, stream>>>(hidden, WsT_f, flag, hn);
        k_hist<<<(N_EDGE + 255) / 256, 256, 0, stream>>>(edges, hist);
        k_scan_part<<<NB_SCAN, 256, 0, stream>>>(hist, startA, bsums);
        k_scan_top<<<1, 256, 0, stream>>>(bsums, boffs);
        k_scan_add<<<NB_SCAN, 256, 0, stream>>>(startA, boffs, cursor);
        k_scat<<<(N_EDGE + 255) / 256, 256, 0, stream>>>(edges, cursor, sorted2);
        k_edge_g<<<N_NODE / 4, 256, 0, stream>>>(sorted2, startA, hist, hn, relcat, atimb,
                                                 W2pk, Wrpk, b2_f, Q_ws, wa_f, Wh_f,
                                                 flag, d_out);
    } else {
        k_edge_c<<<1536, 256, 0, stream>>>(edges, hidden, rela_f, A_rel, A_timeb,
                                           W2T_f, WrT_f, WsT_f, b2_f, Q_ws, wa_f,
                                           flag, bot, d_out);
        k_out<<<N_NODE / 2, 256, 0, stream>>>(bot, Wh_f, d_out, flag);
    }
}

// Round 10
// 1296.577 us; speedup vs baseline: 1.6732x; 1.6732x over previous
//
#include <hip/hip_runtime.h>
#include <hip/hip_bf16.h>

typedef __hip_bfloat16 bf16;
typedef __attribute__((ext_vector_type(8))) short bf16x8;
typedef __attribute__((ext_vector_type(4))) float f32x4;

#define N_NODE   50000
#define N_EDGE   800000
#define N_QUERY  512
#define EPW      8

__device__ __forceinline__ float bfbits2f(unsigned short u) {
    return __uint_as_float(((unsigned)u) << 16);
}
__device__ __forceinline__ unsigned short f2bfbits(float f) {
    unsigned int u = __float_as_uint(f);
    return (unsigned short)((u + 0x7fffu + ((u >> 16) & 1u)) >> 16);  // RNE
}
__device__ __forceinline__ float lrelu(float x) { return x > 0.f ? x : 0.01f * x; }
__device__ __forceinline__ float dot4(float4 a, float4 b, float acc) {
    acc = fmaf(a.x, b.x, acc); acc = fmaf(a.y, b.y, acc);
    acc = fmaf(a.z, b.z, acc); acc = fmaf(a.w, b.w, acc);
    return acc;
}
__device__ __forceinline__ void atom_pk_bf16(unsigned int* addr, float a0, float a1) {
    unsigned int old = *((volatile unsigned int*)addr);
    while (true) {
        float f0 = bfbits2f((unsigned short)(old & 0xffffu)) + a0;
        float f1 = bfbits2f((unsigned short)(old >> 16)) + a1;
        unsigned int nv = (unsigned int)f2bfbits(f0) | ((unsigned int)f2bfbits(f1) << 16);
        unsigned int prev = atomicCAS(addr, old, nv);
        if (prev == old) break;
        old = prev;
    }
}

// ---------- dtype detection (pe[0] word: fp32 -> 0x00000000, bf16 -> 0x3F800000) ----------
__global__ void k_detect(const unsigned int* __restrict__ pe_raw, int* __restrict__ flag) {
    *flag = (pe_raw[0] != 0u) ? 1 : 0;   // 1 = bf16 inputs, 0 = fp32 inputs
}

// ---------- zero accumulators ----------
__global__ void k_zero(unsigned int* __restrict__ out_w, int out_elems,
                       const int* __restrict__ flag,
                       float* __restrict__ bot, float* __restrict__ up, int tier_full) {
    int f = *flag;
    int stride = gridDim.x * blockDim.x;
    int tid = blockIdx.x * blockDim.x + threadIdx.x;
    for (int i = tid; i < N_NODE; i += stride) bot[i] = 0.f;
    if (tier_full) {
        for (int i = tid; i < N_NODE * 128; i += stride) up[i] = 0.f;
    } else {
        int out_words = f ? (out_elems >> 1) : out_elems;
        for (int i = tid; i < out_words; i += stride) out_w[i] = 0u;
    }
}

// ---------- convert all small tensors to fp32 pool (transposes W2/Ws/Wr/Wqr) ----------
#define SEG_RELA   51328
#define SEG_PE     32000
#define SEG_W1     20480
#define SEG_B1     128
#define SEG_W2T    16384
#define SEG_B2     128
#define SEG_WST    8192
#define SEG_WRT    8192
#define SEG_WQRT   8192
#define SEG_BQR    64
#define SEG_WA     64
#define SEG_WH     16384
#define POOL_TOTAL (SEG_RELA+SEG_PE+SEG_W1+SEG_B1+SEG_W2T+SEG_B2+SEG_WST+SEG_WRT+SEG_WQRT+SEG_BQR+SEG_WA+SEG_WH)

__global__ void k_convert(const void* rela, const void* pe, const void* W1, const void* b1,
                          const void* W2, const void* b2, const void* Ws, const void* Wr,
                          const void* Wqr, const void* bqr, const void* walpha, const void* Wh,
                          const int* __restrict__ flag, float* __restrict__ pool) {
    int idx = blockIdx.x * blockDim.x + threadIdx.x;
    int f = *flag;
    auto ld = [&](const void* p, int i) -> float {
        return f ? __bfloat162float(((const bf16*)p)[i]) : ((const float*)p)[i];
    };
    int i = idx;
    if (i < SEG_RELA) { pool[idx] = ld(rela, i); return; } i -= SEG_RELA;
    if (i < SEG_PE)   { pool[idx] = ld(pe, i); return; }   i -= SEG_PE;
    if (i < SEG_W1)   { pool[idx] = ld(W1, i); return; }   i -= SEG_W1;
    if (i < SEG_B1)   { pool[idx] = ld(b1, i); return; }   i -= SEG_B1;
    if (i < SEG_W2T)  { pool[idx] = ld(W2, (i & 127) * 128 + (i >> 7)); return; } i -= SEG_W2T;
    if (i < SEG_B2)   { pool[idx] = ld(b2, i); return; }   i -= SEG_B2;
    if (i < SEG_WST)  { pool[idx] = ld(Ws,  (i & 127) * 64 + (i >> 7)); return; } i -= SEG_WST;
    if (i < SEG_WRT)  { pool[idx] = ld(Wr,  (i & 127) * 64 + (i >> 7)); return; } i -= SEG_WRT;
    if (i < SEG_WQRT) { pool[idx] = ld(Wqr, (i & 127) * 64 + (i >> 7)); return; } i -= SEG_WQRT;
    if (i < SEG_BQR)  { pool[idx] = ld(bqr, i); return; }  i -= SEG_BQR;
    if (i < SEG_WA)   { pool[idx] = ld(walpha, i); return; } i -= SEG_WA;
    if (i < SEG_WH)   { pool[idx] = ld(Wh, i); return; }
}

// ---------- pack W2/Wr into MFMA B-fragment order (bf16) ----------
__global__ void k_pack(const float* __restrict__ W2T_f, const float* __restrict__ WrT_f,
                       short* __restrict__ W2pk, short* __restrict__ Wrpk) {
    int idx = blockIdx.x * blockDim.x + threadIdx.x;
    if (idx < 16384) {
        int j = idx & 7, lane = (idx >> 3) & 63, kb = (idx >> 9) & 3, nt = idx >> 11;
        int k = kb * 32 + (lane >> 4) * 8 + j, n = nt * 16 + (lane & 15);
        W2pk[idx] = (short)f2bfbits(W2T_f[n * 128 + k]);
    } else if (idx < 16384 + 8192) {
        int i2 = idx - 16384;
        int j = i2 & 7, lane = (i2 >> 3) & 63, kb = (i2 >> 9) & 3, nt = i2 >> 11;
        int k = kb * 32 + (lane >> 4) * 8 + j, n = nt * 16 + (lane & 15);
        Wrpk[i2] = (short)f2bfbits(WrT_f[n * 128 + k]);
    }
}

// ---------- precompute tables ----------
__global__ void k_arel(const float* __restrict__ rela_f, const float* __restrict__ W1_f,
                       float* __restrict__ A_rel, unsigned short* __restrict__ relcat) {
    __shared__ float ld[128];
    int r = blockIdx.x, j = threadIdx.x;
    float rv = rela_f[r * 128 + j];
    ld[j] = rv;
    __syncthreads();
    float acc = 0.f;
    for (int k = 0; k < 128; k++) acc = fmaf(ld[k], W1_f[k * 128 + j], acc);
    A_rel[r * 128 + j] = acc;
    relcat[r * 256 + j] = f2bfbits(acc);
    relcat[r * 256 + 128 + j] = f2bfbits(rv);
}

__global__ void k_atime(const float* __restrict__ pe_f, const float* __restrict__ W1_f,
                        const float* __restrict__ b1_f, float* __restrict__ A_timeb,
                        unsigned short* __restrict__ atimb) {
    __shared__ float ld[32];
    int t = blockIdx.x, j = threadIdx.x;
    if (j < 32) ld[j] = pe_f[t * 32 + j];
    __syncthreads();
    float acc = b1_f[j];
    for (int k = 0; k < 32; k++) acc = fmaf(ld[k], W1_f[(128 + k) * 128 + j], acc);
    A_timeb[t * 128 + j] = acc;
    atimb[t * 128 + j] = f2bfbits(acc);
}

__global__ void k_qws(const float* __restrict__ rela_f, const int* __restrict__ q_rel,
                      const float* __restrict__ bqr_f, const float* __restrict__ WqrT_f,
                      float* __restrict__ Q_ws) {
    alignas(16) __shared__ float qrow[4][128];
    int wv = threadIdx.x >> 6, lane = threadIdx.x & 63;
    int q = blockIdx.x * 4 + wv;
    int qr = q_rel[q];
    const float2* rp = (const float2*)(rela_f + qr * 128);
    float2 rv = rp[lane];
    qrow[wv][2 * lane] = rv.x;
    qrow[wv][2 * lane + 1] = rv.y;
    __syncthreads();
    const float4* wp = (const float4*)(WqrT_f + lane * 128);
    const float4* qp4 = (const float4*)qrow[wv];
    float acc = bqr_f[lane];
    for (int k4 = 0; k4 < 32; k4++) acc = dot4(qp4[k4], wp[k4], acc);
    Q_ws[q * 64 + lane] = acc;
}

// S_b bf16 [50000][64] = hidden[n] . Ws  (full tier only)
__global__ void k_snode(const void* __restrict__ hidden, const float* __restrict__ WsT_f,
                        const int* __restrict__ flag, unsigned short* __restrict__ S_b) {
    alignas(16) __shared__ float hrow[4][128];
    int wv = threadIdx.x >> 6, lane = threadIdx.x & 63;
    int n = blockIdx.x * 4 + wv;
    int f = *flag;
    if (f) {
        ushort2 hv = ((const ushort2*)((const bf16*)hidden + n * 128))[lane];
        hrow[wv][2 * lane] = bfbits2f(hv.x);
        hrow[wv][2 * lane + 1] = bfbits2f(hv.y);
    } else {
        float2 hv = ((const float2*)((const float*)hidden + n * 128))[lane];
        hrow[wv][2 * lane] = hv.x;
        hrow[wv][2 * lane + 1] = hv.y;
    }
    __syncthreads();
    const float4* wp = (const float4*)(WsT_f + lane * 128);
    const float4* hp4 = (const float4*)hrow[wv];
    float acc = 0.f;
    for (int k4 = 0; k4 < 32; k4++) acc = dot4(hp4[k4], wp[k4], acc);
    S_b[n * 64 + lane] = f2bfbits(acc);
}

// ---------- SCATTER edge kernel: MFMA, packed indices, single LDS buf ----------
__global__ __launch_bounds__(256) void k_edge_s(
        const int* __restrict__ edges, const void* __restrict__ hidden,
        const unsigned short* __restrict__ relcat,   // [r][256] A_rel|rela bf16
        const unsigned short* __restrict__ atimb,    // [t][128] bf16
        const short* __restrict__ W2pk, const short* __restrict__ Wrpk,
        const float* __restrict__ b2_f, const unsigned short* __restrict__ S_b,
        const float* __restrict__ Q_ws, const float* __restrict__ wa_f,
        const int* __restrict__ flag,
        float* __restrict__ up, float* __restrict__ bot) {
    alignas(16) __shared__ short buf[4][16][136];   // wave-private h -> hr buffer
    int wv = threadIdx.x >> 6, lane = threadIdx.x & 63;
    int c = lane & 15, q = lane >> 4;
    int f = *flag;
    int nwaves = gridDim.x * 4;
    const int ngroups = N_EDGE / 16;  // 50000 exact

    float wa4[4];
#pragma unroll
    for (int nt = 0; nt < 4; nt++) wa4[nt] = wa_f[nt * 16 + c];

    short (*bw)[136] = buf[wv];

    for (int g = blockIdx.x * 4 + wv; g < ngroups; g += nwaves) {
        int base = g * 16;

        // lane e (<16) holds edge e's packed fields
        int w0 = 0, w1 = 0, w2 = 0;
        if (lane < 16) {
            const int* ep = edges + (base + lane) * 7;
            w0 = ep[4] | (ep[0] << 16);   // sub | qi<<16   (both < 65536)
            w1 = ep[2] | (ep[6] << 16);   // rel | tim<<16
            w2 = ep[5];                   // obj
        }

        // stage h = lrelu(A_rel + A_timeb) (bf16 coalesced reads) into LDS
#pragma unroll
        for (int e = 0; e < 16; e++) {
            int w1e = __shfl(w1, e);
            int rel_e = w1e & 0xffff, tim_e = w1e >> 16;
            ushort2 a = ((const ushort2*)(relcat + rel_e * 256))[lane];
            ushort2 t = ((const ushort2*)(atimb + tim_e * 128))[lane];
            float h0 = lrelu(bfbits2f(a.x) + bfbits2f(t.x));
            float h1 = lrelu(bfbits2f(a.y) + bfbits2f(t.y));
            *((unsigned int*)&bw[e][2 * lane]) =
                (unsigned)f2bfbits(h0) | ((unsigned)f2bfbits(h1) << 16);
        }

        bf16x8 hf[4];
#pragma unroll
        for (int kb = 0; kb < 4; kb++)
            hf[kb] = *((const bf16x8*)&bw[c][kb * 32 + q * 8]);

        // h2 = lrelu(h@W2 + b2) -> buf (D-layout writes)
#pragma unroll
        for (int nt = 0; nt < 8; nt++) {
            f32x4 acc = {0.f, 0.f, 0.f, 0.f};
#pragma unroll
            for (int kb = 0; kb < 4; kb++) {
                bf16x8 bfr = *((const bf16x8*)(W2pk + (((nt * 4 + kb) * 64) + lane) * 8));
                acc = __builtin_amdgcn_mfma_f32_16x16x32_bf16(hf[kb], bfr, acc, 0, 0, 0);
            }
            int colg = nt * 16 + c;
            float b2v = b2_f[colg];
#pragma unroll
            for (int r = 0; r < 4; r++) {
                int er = q * 4 + r;
                bw[er][colg] = (short)f2bfbits(lrelu(acc[r] + b2v));
            }
        }

        // hr = h2 + rel_e: coalesced rela read + LDS fixup
#pragma unroll
        for (int e = 0; e < 16; e++) {
            int rel_e = __shfl(w1, e) & 0xffff;
            ushort2 rv = ((const ushort2*)(relcat + rel_e * 256 + 128))[lane];
            unsigned int pk = *((const unsigned int*)&bw[e][2 * lane]);
            float v0 = bfbits2f((unsigned short)(pk & 0xffffu)) + bfbits2f(rv.x);
            float v1 = bfbits2f((unsigned short)(pk >> 16)) + bfbits2f(rv.y);
            *((unsigned int*)&bw[e][2 * lane]) =
                (unsigned)f2bfbits(v0) | ((unsigned)f2bfbits(v1) << 16);
        }

        bf16x8 hrf[4];
#pragma unroll
        for (int kb = 0; kb < 4; kb++)
            hrf[kb] = *((const bf16x8*)&bw[c][kb * 32 + q * 8]);

        // att = lrelu(S_node + Q_ws + hr@Wr) . w_alpha
        float asum[4] = {0.f, 0.f, 0.f, 0.f};
#pragma unroll
        for (int nt = 0; nt < 4; nt++) {
            f32x4 acc = {0.f, 0.f, 0.f, 0.f};
#pragma unroll
            for (int kb = 0; kb < 4; kb++) {
                bf16x8 bfr = *((const bf16x8*)(Wrpk + (((nt * 4 + kb) * 64) + lane) * 8));
                acc = __builtin_amdgcn_mfma_f32_16x16x32_bf16(hrf[kb], bfr, acc, 0, 0, 0);
            }
            int colg = nt * 16 + c;
#pragma unroll
            for (int r = 0; r < 4; r++) {
                int er = q * 4 + r;
                int w0e = __shfl(w0, er);
                int sub_e = w0e & 0xffff, qi_e = w0e >> 16;
                float av = acc[r] + bfbits2f(S_b[sub_e * 64 + colg])
                         + Q_ws[qi_e * 64 + colg];
                asum[r] += lrelu(av) * wa4[nt];
            }
        }
        float ea[4];
#pragma unroll
        for (int r = 0; r < 4; r++) {
            float a = asum[r];
            a += __shfl_xor(a, 1); a += __shfl_xor(a, 2);
            a += __shfl_xor(a, 4); a += __shfl_xor(a, 8);
            ea[r] = __expf(a);
        }

        // scatter: up[obj] += ea*(hidden[sub]+hr), bot[obj] += ea
#pragma unroll
        for (int e = 0; e < 16; e++) {
            float eav = __shfl(ea[e & 3], (e >> 2) * 16);
            int obj_e = __shfl(w2, e);
            int sub_e = __shfl(w0, e) & 0xffff;
            unsigned int pk = *((const unsigned int*)&bw[e][2 * lane]);
            float hr0 = bfbits2f((unsigned short)(pk & 0xffffu));
            float hr1 = bfbits2f((unsigned short)(pk >> 16));
            float hs0, hs1;
            if (f) {
                ushort2 hv = ((const ushort2*)((const bf16*)hidden + sub_e * 128))[lane];
                hs0 = bfbits2f(hv.x); hs1 = bfbits2f(hv.y);
            } else {
                float2 hv = ((const float2*)((const float*)hidden + sub_e * 128))[lane];
                hs0 = hv.x; hs1 = hv.y;
            }
            float* dst = up + obj_e * 128 + 2 * lane;
            unsafeAtomicAdd(dst,     eav * (hs0 + hr0));
            unsafeAtomicAdd(dst + 1, eav * (hs1 + hr1));
            if (lane == 0) unsafeAtomicAdd(bot + obj_e, eav);
        }
    }
}

// ---------- COMPACT-tier fallback (atomics into d_out) ----------
__global__ __launch_bounds__(256) void k_edge_c(
        const int* __restrict__ edges, const void* __restrict__ hidden,
        const float* __restrict__ rela_f,
        const float* __restrict__ A_rel, const float* __restrict__ A_timeb,
        const float* __restrict__ W2T, const float* __restrict__ WrT,
        const float* __restrict__ WsT, const float* __restrict__ b2_f,
        const float* __restrict__ Q_ws, const float* __restrict__ wa_f,
        const int* __restrict__ flag,
        float* __restrict__ bot, void* __restrict__ dout) {
    alignas(16) __shared__ float lds_h[4][EPW][128];
    alignas(16) __shared__ float lds_hr[4][EPW][128];
    alignas(16) __shared__ float lds_hs[4][EPW][128];
    int wv = threadIdx.x >> 6, lane = threadIdx.x & 63;
    int f = *flag;
    int nwaves = gridDim.x * 4;
    const int ngroups = N_EDGE / EPW;
    float b20 = b2_f[2 * lane], b21 = b2_f[2 * lane + 1];
    float wa = wa_f[lane];
    for (int g = blockIdx.x * 4 + wv; g < ngroups; g += nwaves) {
        int base = g * EPW;
        int rel[EPW], sub[EPW], obj[EPW], qi[EPW], tim[EPW];
#pragma unroll
        for (int e = 0; e < EPW; e++) {
            const int* ep = edges + (base + e) * 7;
            qi[e] = ep[0]; rel[e] = ep[2]; sub[e] = ep[4];
            obj[e] = ep[5]; tim[e] = ep[6];
        }
        float hs0[EPW], hs1[EPW];
#pragma unroll
        for (int e = 0; e < EPW; e++) {
            const float2* ar = (const float2*)(A_rel + rel[e] * 128);
            const float2* at = (const float2*)(A_timeb + tim[e] * 128);
            float2 a = ar[lane], t = at[lane];
            lds_h[wv][e][2 * lane]     = lrelu(a.x + t.x);
            lds_h[wv][e][2 * lane + 1] = lrelu(a.y + t.y);
            if (f) {
                ushort2 hv = ((const ushort2*)((const bf16*)hidden + sub[e] * 128))[lane];
                hs0[e] = bfbits2f(hv.x); hs1[e] = bfbits2f(hv.y);
            } else {
                float2 hv = ((const float2*)((const float*)hidden + sub[e] * 128))[lane];
                hs0[e] = hv.x; hs1[e] = hv.y;
            }
            lds_hs[wv][e][2 * lane]     = hs0[e];
            lds_hs[wv][e][2 * lane + 1] = hs1[e];
        }
        float acc0[EPW], acc1[EPW];
#pragma unroll
        for (int e = 0; e < EPW; e++) { acc0[e] = b20; acc1[e] = b21; }
        const float4* w0p = (const float4*)(W2T + (2 * lane) * 128);
        const float4* w1p = (const float4*)(W2T + (2 * lane + 1) * 128);
        for (int k4 = 0; k4 < 32; k4++) {
            float4 w0 = w0p[k4], w1 = w1p[k4];
#pragma unroll
            for (int e = 0; e < EPW; e++) {
                float4 h = ((const float4*)lds_h[wv][e])[k4];
                acc0[e] = dot4(h, w0, acc0[e]);
                acc1[e] = dot4(h, w1, acc1[e]);
            }
        }
        float hr0[EPW], hr1[EPW];
#pragma unroll
        for (int e = 0; e < EPW; e++) {
            const float2* rp = (const float2*)(rela_f + rel[e] * 128);
            float2 rv = rp[lane];
            hr0[e] = lrelu(acc0[e]) + rv.x;
            hr1[e] = lrelu(acc1[e]) + rv.y;
            lds_hr[wv][e][2 * lane]     = hr0[e];
            lds_hr[wv][e][2 * lane + 1] = hr1[e];
        }
        float att[EPW];
#pragma unroll
        for (int e = 0; e < EPW; e++) att[e] = Q_ws[qi[e] * 64 + lane];
        const float4* wrp = (const float4*)(WrT + lane * 128);
        const float4* wsp = (const float4*)(WsT + lane * 128);
        for (int k4 = 0; k4 < 32; k4++) {
            float4 w = wrp[k4], w2 = wsp[k4];
#pragma unroll
            for (int e = 0; e < EPW; e++) {
                float4 hr4 = ((const float4*)lds_hr[wv][e])[k4];
                float4 hs4 = ((const float4*)lds_hs[wv][e])[k4];
                att[e] = dot4(hr4, w, att[e]);
                att[e] = dot4(hs4, w2, att[e]);
            }
        }
        float ea[EPW];
#pragma unroll
        for (int e = 0; e < EPW; e++) {
            float a = lrelu(att[e]) * wa;
            a += __shfl_xor(a, 32); a += __shfl_xor(a, 16); a += __shfl_xor(a, 8);
            a += __shfl_xor(a, 4);  a += __shfl_xor(a, 2);  a += __shfl_xor(a, 1);
            ea[e] = __expf(a);
        }
#pragma unroll
        for (int e = 0; e < EPW; e++) {
            float v0 = ea[e] * (hs0[e] + hr0[e]);
            float v1 = ea[e] * (hs1[e] + hr1[e]);
            if (!f) {
                float* dst = (float*)dout + obj[e] * 128 + 2 * lane;
                unsafeAtomicAdd(dst,     v0);
                unsafeAtomicAdd(dst + 1, v1);
            } else {
                atom_pk_bf16((unsigned int*)dout + obj[e] * 64 + lane, v0, v1);
            }
            if (lane == 0) unsafeAtomicAdd(bot + obj[e], ea[e]);
        }
    }
}

// ---------- epilogue: out[n] = (up[n]/bot[n]) @ Wh, dtype/tier-polymorphic ----------
__global__ void k_out(const float* __restrict__ up, const float* __restrict__ bot,
                      const float* __restrict__ Wh_f, void* __restrict__ dout,
                      const int* __restrict__ flag, int tier_full) {
    __shared__ float m[2][128];
    int half = threadIdx.x >> 7, j = threadIdx.x & 127;
    int n = blockIdx.x * 2 + half;
    int f = *flag;
    float inv = 1.f / (bot[n] + 1e-5f);
    float num;
    if (tier_full) {
        num = up[n * 128 + j];
    } else if (!f) {
        num = ((const float*)dout)[n * 128 + j];
    } else {
        unsigned int w = ((const unsigned int*)dout)[n * 64 + (j >> 1)];
        num = bfbits2f((unsigned short)((j & 1) ? (w >> 16) : (w & 0xffffu)));
    }
    m[half][j] = num * inv;
    __syncthreads();
    float acc = 0.f;
    for (int k = 0; k < 128; k++) acc = fmaf(m[half][k], Wh_f[k * 128 + j], acc);
    if (f) ((bf16*)dout)[n * 128 + j] = __float2bfloat16(acc);
    else   ((float*)dout)[n * 128 + j] = acc;
}

// ---------- launcher ----------
extern "C" void kernel_launch(void* const* d_in, const int* in_sizes, int n_in,
                              void* d_out, int out_size, void* d_ws, size_t ws_size,
                              hipStream_t stream) {
    const void* hidden = d_in[0];
    const void* rela   = d_in[1];
    const void* pe     = d_in[2];
    const void* W1     = d_in[3];
    const void* b1     = d_in[4];
    const void* W2     = d_in[5];
    const void* b2     = d_in[6];
    const void* Ws     = d_in[7];
    const void* Wr     = d_in[8];
    const void* Wqr    = d_in[9];
    const void* bqr    = d_in[10];
    const void* walpha = d_in[11];
    const void* Wh     = d_in[12];
    const int* q_rel   = (const int*)d_in[13];
    const int* edges   = (const int*)d_in[14];

    float* ws = (float*)d_ws;
    size_t off = 0;
    int*   flag    = (int*)(ws + off); off += 4;
    float* pool    = ws + off;
    float* rela_f  = pool;
    float* pe_f    = rela_f + SEG_RELA;
    float* W1_f    = pe_f + SEG_PE;
    float* b1_f    = W1_f + SEG_W1;
    float* W2T_f   = b1_f + SEG_B1;
    float* b2_f    = W2T_f + SEG_W2T;
    float* WsT_f   = b2_f + SEG_B2;
    float* WrT_f   = WsT_f + SEG_WST;
    float* WqrT_f  = WrT_f + SEG_WRT;
    float* bqr_f   = WqrT_f + SEG_WQRT;
    float* wa_f    = bqr_f + SEG_BQR;
    float* Wh_f    = wa_f + SEG_WA;
    off += POOL_TOTAL;
    float* A_rel   = ws + off; off += 401 * 128;
    float* A_timeb = ws + off; off += 1000 * 128;
    float* Q_ws    = ws + off; off += N_QUERY * 64;
    float* bot     = ws + off; off += N_NODE;
    short* W2pk    = (short*)(ws + off); off += 8192;
    short* Wrpk    = (short*)(ws + off); off += 4096;
    unsigned short* relcat = (unsigned short*)(ws + off); off += 401 * 128;   // 401*256 bf16
    unsigned short* atimb  = (unsigned short*)(ws + off); off += 1000 * 64;   // 1000*128 bf16
    unsigned short* S_b    = (unsigned short*)(ws + off); off += (size_t)N_NODE * 32; // 50000*64 bf16
    float* up      = ws + off; off += (size_t)N_NODE * 128;
    size_t full_floats = off;   // ~8.55M floats = 34.2 MB (proven ws >= 39.6 MB)

    int tier_full = (ws_size >= full_floats * sizeof(float)) ? 1 : 0;

    k_detect<<<1, 1, 0, stream>>>((const unsigned int*)pe, flag);
    k_zero<<<2048, 256, 0, stream>>>((unsigned int*)d_out, out_size, flag, bot, up, tier_full);
    k_convert<<<(POOL_TOTAL + 255) / 256, 256, 0, stream>>>(
        rela, pe, W1, b1, W2, b2, Ws, Wr, Wqr, bqr, walpha, Wh, flag, pool);
    k_arel<<<401, 128, 0, stream>>>(rela_f, W1_f, A_rel, relcat);
    k_atime<<<1000, 128, 0, stream>>>(pe_f, W1_f, b1_f, A_timeb, atimb);
    k_qws<<<N_QUERY / 4, 256, 0, stream>>>(rela_f, q_rel, bqr_f, WqrT_f, Q_ws);

    if (tier_full) {
        k_pack<<<96, 256, 0, stream>>>(W2T_f, WrT_f, W2pk, Wrpk);
        k_snode<<<N_NODE / 4, 256, 0, stream>>>(hidden, WsT_f, flag, S_b);
        k_edge_s<<<1024, 256, 0, stream>>>(edges, hidden, relcat, atimb, W2pk, Wrpk,
                                           b2_f, S_b, Q_ws, wa_f, flag, up, bot);
    } else {
        k_edge_c<<<1536, 256, 0, stream>>>(edges, hidden, rela_f, A_rel, A_timeb,
                                           W2T_f, WrT_f, WsT_f, b2_f, Q_ws, wa_f,
                                           flag, bot, d_out);
    }

    k_out<<<N_NODE / 2, 256, 0, stream>>>(up, bot, Wh_f, d_out, flag, tier_full);
}